// Round 1
// baseline (5594.199 us; speedup 1.0000x reference)
//
#include <hip/hip_runtime.h>
#include <hip/hip_bf16.h>
#include <float.h>

// Problem constants
#define BQ    64      // batch
#define CDIM  640     // channels (K)
#define LQ    441     // query descriptors per image
#define NCLS  32      // support classes
#define MS    2205    // support descriptors per class
#define ITILES 7      // 7*64 = 448 padded rows
#define JCHUNK 256    // j-chunk width
#define NJC    9      // 9*256 = 2304 padded cols
#define KCH    64     // k-chunk
#define NKC    10     // 640/64
#define AROW   72     // padded row length (bf16 elems): 64 k + 8 pad -> 144B rows, 16B aligned, 2-way banks
#define NEG_INF (-3.0e38f)

typedef __attribute__((ext_vector_type(8))) short short8;
typedef __attribute__((ext_vector_type(4))) float f32x4;

__device__ __forceinline__ void ins3(float s, float& a, float& b, float& c) {
  // insert s into sorted (a>=b>=c), keep top-3: 5 VALU ops
  float x0 = fmaxf(a, s), x1 = fminf(a, s);
  float y1 = fmaxf(b, x1), y2 = fminf(b, x1);
  a = x0; b = y1; c = fmaxf(c, y2);
}

// ---------------- prep: normalize x1 over C, transpose to [b][it][kc][64 i][72 k] bf16 ----------------
__global__ __launch_bounds__(256) void prep_q(const float* __restrict__ x1,
                                              unsigned short* __restrict__ Abf) {
  const int it = blockIdx.x;   // 0..6
  const int b  = blockIdx.y;   // 0..63
  const int t  = threadIdx.x;
  const int il = t & 63, cg = t >> 6;
  __shared__ float red[4][64];
  __shared__ float rnq[64];
  __shared__ unsigned short tile[64][66];   // [c][i], padded to break bank conflicts

  const int i = it * 64 + il;
  float ss = 0.f;
  if (i < LQ) {
    for (int c = cg; c < CDIM; c += 4) {
      float v = x1[((size_t)b * CDIM + c) * LQ + i];
      ss += v * v;
    }
  }
  red[cg][il] = ss;
  __syncthreads();
  if (t < 64) {
    float s = red[0][t] + red[1][t] + red[2][t] + red[3][t];
    rnq[t] = (it * 64 + t < LQ) ? rsqrtf(s) : 0.f;
  }
  __syncthreads();

  for (int kc = 0; kc < NKC; ++kc) {
    for (int idx = t; idx < 4096; idx += 256) {
      int cc = idx >> 6, ii = idx & 63;       // lanes: consecutive i -> coalesced global read
      int gi = it * 64 + ii;
      float v = 0.f;
      if (gi < LQ) v = x1[((size_t)b * CDIM + kc * 64 + cc) * LQ + gi] * rnq[ii];
      __hip_bfloat16 h = __float2bfloat16(v);
      tile[cc][ii] = *(unsigned short*)&h;
    }
    __syncthreads();
    unsigned int* blob = (unsigned int*)(Abf + ((size_t)(b * ITILES + it) * NKC + kc) * (64 * AROW));
    for (int idx = t; idx < 2048; idx += 256) {
      int row = idx >> 5, kp = idx & 31;      // lanes: consecutive kp -> coalesced global write
      unsigned int lo = tile[kp * 2][row], hi = tile[kp * 2 + 1][row];
      blob[row * (AROW / 2) + kp] = lo | (hi << 16);
    }
    __syncthreads();
  }
}

// ---------------- prep: normalize x2 over C, transpose to [n][jc][kc][256 j][72 k] bf16 ----------------
__global__ __launch_bounds__(256) void prep_s(const float* __restrict__ x2,
                                              unsigned short* __restrict__ Bbf) {
  const int jc = blockIdx.x;   // 0..8
  const int n  = blockIdx.y;   // 0..31
  const int t  = threadIdx.x;
  __shared__ float rns[256];
  __shared__ unsigned short tile[64][66];

  const int j = jc * 256 + t;
  float ss = 0.f;
  if (j < MS) {
    for (int c = 0; c < CDIM; ++c) {
      float v = x2[((size_t)n * CDIM + c) * MS + j];
      ss += v * v;
    }
  }
  rns[t] = (j < MS) ? rsqrtf(ss) : 0.f;
  __syncthreads();

  for (int jt = 0; jt < 4; ++jt) {
    for (int kc = 0; kc < NKC; ++kc) {
      for (int idx = t; idx < 4096; idx += 256) {
        int cc = idx >> 6, jj = idx & 63;
        int gj = jc * 256 + jt * 64 + jj;
        float v = 0.f;
        if (gj < MS) v = x2[((size_t)n * CDIM + kc * 64 + cc) * MS + gj] * rns[jt * 64 + jj];
        __hip_bfloat16 h = __float2bfloat16(v);
        tile[cc][jj] = *(unsigned short*)&h;   // zero rows for padded j -> safe (also masked at top-k)
      }
      __syncthreads();
      unsigned int* blob = (unsigned int*)(Bbf + ((size_t)(n * NJC + jc) * NKC + kc) * (JCHUNK * AROW));
      for (int idx = t; idx < 2048; idx += 256) {
        int row = idx >> 5, kp = idx & 31;
        unsigned int lo = tile[kp * 2][row], hi = tile[kp * 2 + 1][row];
        blob[(jt * 64 + row) * (AROW / 2) + kp] = lo | (hi << 16);
      }
      __syncthreads();
    }
  }
}

// ---------------- main: fused bf16 MFMA GEMM + running top-3 + reduce ----------------
// grid (448, 32): x = b*7+it (64-row tile), y = class n. block = 256 = 4 waves,
// wave w computes rows 0..63 x cols w*64..w*64+63 of each 256-wide j-chunk.
__global__ __launch_bounds__(256) void gemm_topk(const unsigned short* __restrict__ Abf,
                                                 const unsigned short* __restrict__ Bbf,
                                                 float* __restrict__ out) {
  const int bx   = blockIdx.x;           // 0..447
  const int b    = bx / ITILES;
  const int it   = bx % ITILES;
  const int n    = blockIdx.y;
  const int t    = threadIdx.x;
  const int lane = t & 63, wave = t >> 6;
  const int l15  = lane & 15, q = lane >> 4;

  __shared__ __align__(16) char smem[52224];
  unsigned short* Al = (unsigned short*)smem;            // 64*72 bf16 = 9216 B
  unsigned short* Bl = (unsigned short*)(smem + 9216);   // 256*72 bf16 = 36864 B
  float* mrg = (float*)smem;                             // reuse: 64 rows * 64 lanes * 3 = 49152 B
  float* aux = (float*)(smem + 49152);                   // 64 rows * 4 segs * 3 = 3072 B

  float t3[16][3];
  #pragma unroll
  for (int r = 0; r < 16; ++r) { t3[r][0] = NEG_INF; t3[r][1] = NEG_INF; t3[r][2] = NEG_INF; }

  const int wj = wave * 64;
  const size_t Abase = (size_t)(b * ITILES + it) * NKC * (64 * AROW);

  for (int mc = 0; mc < NJC; ++mc) {
    f32x4 acc[4][4];
    #pragma unroll
    for (int r = 0; r < 4; ++r)
      #pragma unroll
      for (int c = 0; c < 4; ++c) acc[r][c] = (f32x4){0.f, 0.f, 0.f, 0.f};

    const size_t Bbase = (size_t)(n * NJC + mc) * NKC * (JCHUNK * AROW);
    for (int kc = 0; kc < NKC; ++kc) {
      __syncthreads();                      // previous k-chunk's fragment reads done
      {                                     // stage A slice: 9216 B = 576 int4
        const int4* gA = (const int4*)(Abf + Abase + (size_t)kc * (64 * AROW));
        int4* sA = (int4*)Al;
        #pragma unroll
        for (int rep = 0; rep < 3; ++rep) {
          int idx = t + rep * 256;
          if (idx < 576) sA[idx] = gA[idx];
        }
        // stage B slice: 36864 B = 2304 int4
        const int4* gB = (const int4*)(Bbf + Bbase + (size_t)kc * (JCHUNK * AROW));
        int4* sB = (int4*)Bl;
        #pragma unroll
        for (int rep = 0; rep < 9; ++rep) sB[t + rep * 256] = gB[t + rep * 256];
      }
      __syncthreads();
      #pragma unroll
      for (int ks = 0; ks < 2; ++ks) {      // two K=32 MFMA steps
        short8 af[4], bfr[4];
        #pragma unroll
        for (int r = 0; r < 4; ++r)
          af[r] = *(const short8*)&Al[(r * 16 + l15) * AROW + ks * 32 + q * 8];
        #pragma unroll
        for (int c = 0; c < 4; ++c)
          bfr[c] = *(const short8*)&Bl[(wj + c * 16 + l15) * AROW + ks * 32 + q * 8];
        #pragma unroll
        for (int r = 0; r < 4; ++r)
          #pragma unroll
          for (int c = 0; c < 4; ++c)
            acc[r][c] = __builtin_amdgcn_mfma_f32_16x16x32_bf16(af[r], bfr[c], acc[r][c], 0, 0, 0);
      }
    }

    // fold this j-chunk's 64 scores/lane into running top-3 (5 ops each)
    #pragma unroll
    for (int c = 0; c < 4; ++c) {
      const int jg = mc * JCHUNK + wj + c * 16 + l15;
      const bool jv = jg < MS;              // mask padded support columns
      #pragma unroll
      for (int r = 0; r < 4; ++r)
        #pragma unroll
        for (int reg = 0; reg < 4; ++reg) {
          float s = jv ? acc[r][c][reg] : NEG_INF;
          ins3(s, t3[r * 4 + reg][0], t3[r * 4 + reg][1], t3[r * 4 + reg][2]);
        }
    }
  }

  // ---- merge per-lane top-3 across the 64 lanes holding each row ----
  __syncthreads();                          // done with Al/Bl; reuse as mrg
  #pragma unroll
  for (int r = 0; r < 4; ++r)
    #pragma unroll
    for (int reg = 0; reg < 4; ++reg) {
      int row = r * 16 + q * 4 + reg;       // C/D layout: row = quad*4 + reg (m89-verified)
      int col = wave * 16 + l15;
      float* p = &mrg[(row * 64 + col) * 3];
      p[0] = t3[r * 4 + reg][0]; p[1] = t3[r * 4 + reg][1]; p[2] = t3[r * 4 + reg][2];
    }
  __syncthreads();
  {
    int row = t >> 2, seg = t & 3;          // 4 threads per row, 16 cols each
    float a = NEG_INF, bb = NEG_INF, cc = NEG_INF;
    for (int c0 = seg * 16; c0 < seg * 16 + 16; ++c0) {
      const float* p = &mrg[(row * 64 + c0) * 3];
      ins3(p[0], a, bb, cc); ins3(p[1], a, bb, cc); ins3(p[2], a, bb, cc);
    }
    aux[(row * 4 + seg) * 3 + 0] = a;
    aux[(row * 4 + seg) * 3 + 1] = bb;
    aux[(row * 4 + seg) * 3 + 2] = cc;
  }
  __syncthreads();
  if (t < 64) {                             // wave 0: final top-3 per row, sum rows, one atomic
    float a = NEG_INF, bb = NEG_INF, cc = NEG_INF;
    for (int v = 0; v < 12; ++v) ins3(aux[t * 12 + v], a, bb, cc);
    float sum = a + bb + cc;                // padded rows: scores were exactly 0 -> sum 0
    for (int off = 32; off > 0; off >>= 1) sum += __shfl_down(sum, off);
    if (t == 0) atomicAdd(&out[b * NCLS + n], sum);
  }
}

extern "C" void kernel_launch(void* const* d_in, const int* in_sizes, int n_in,
                              void* d_out, int out_size, void* d_ws, size_t ws_size,
                              hipStream_t stream) {
  const float* x1 = (const float*)d_in[0];   // [64, 640, 441] fp32
  const float* x2 = (const float*)d_in[1];   // [32, 640, 2205] fp32
  float* out = (float*)d_out;                // [64, 32] fp32

  // workspace layout: A_bf 41,287,680 B | B_bf 106,168,320 B  (total ~140.6 MiB)
  unsigned short* Abf = (unsigned short*)d_ws;
  unsigned short* Bbf = (unsigned short*)((char*)d_ws + (size_t)BQ * ITILES * NKC * 64 * AROW * 2);

  hipMemsetAsync(d_out, 0, BQ * NCLS * sizeof(float), stream);  // atomics accumulate into zeros
  prep_q<<<dim3(ITILES, BQ), 256, 0, stream>>>(x1, Abf);
  prep_s<<<dim3(NJC, NCLS), 256, 0, stream>>>(x2, Bbf);
  gemm_topk<<<dim3(BQ * ITILES, NCLS), 256, 0, stream>>>(Abf, Bbf, out);
}

// Round 2
// 3120.549 us; speedup vs baseline: 1.7927x; 1.7927x over previous
//
#include <hip/hip_runtime.h>
#include <hip/hip_bf16.h>
#include <float.h>

// Problem constants
#define BQ    64      // batch
#define CDIM  640     // channels (K)
#define LQ    441     // query descriptors per image
#define NCLS  32      // support classes
#define MS    2205    // support descriptors per class
#define ITILES 7      // 7*64 = 448 padded rows
#define JCHUNK 256    // j-chunk width
#define NJC    9      // 9*256 = 2304 padded cols
#define NKC    10     // 640/64 k-chunks
#define NEG_INF (-3.0e38f)

// A blob: per (b,it) row-major 64 rows x 640 k bf16 = 81920 B (5120 x 16B granules, 80/row)
#define ABYTES 81920
#define ADW    20480
// B blob: per (n,mc): [kc][ks][jf][lane] x 16B = 10*2*16*64*16 = 327680 B; per-kc chunk 32768 B
#define BMC    327680
#define BN     (NJC * BMC)   // 2,949,120 B per class

typedef __attribute__((ext_vector_type(8))) short short8;
typedef __attribute__((ext_vector_type(4))) float f32x4;

__device__ __forceinline__ void ins3(float s, float& a, float& b, float& c) {
  float x0 = fmaxf(a, s), x1 = fminf(a, s);
  float y1 = fmaxf(b, x1), y2 = fminf(b, x1);
  a = x0; b = y1; c = fmaxf(c, y2);
}

// ---------------- prep: normalize x1 over C, emit row-major bf16 A tiles [b*7+it][64 i][640 k] ----------------
__global__ __launch_bounds__(256) void prep_q(const float* __restrict__ x1,
                                              unsigned short* __restrict__ Abf) {
  const int it = blockIdx.x;   // 0..6
  const int b  = blockIdx.y;   // 0..63
  const int t  = threadIdx.x;
  const int il = t & 63, cg = t >> 6;
  __shared__ float red[4][64];
  __shared__ float rnq[64];
  __shared__ unsigned short tile[64][66];   // [c][i]

  const int i = it * 64 + il;
  float ss = 0.f;
  if (i < LQ) {
    for (int c = cg; c < CDIM; c += 4) {
      float v = x1[((size_t)b * CDIM + c) * LQ + i];
      ss += v * v;
    }
  }
  red[cg][il] = ss;
  __syncthreads();
  if (t < 64) {
    float s = red[0][t] + red[1][t] + red[2][t] + red[3][t];
    rnq[t] = (it * 64 + t < LQ) ? rsqrtf(s) : 0.f;
  }
  __syncthreads();

  unsigned int* blob = (unsigned int*)Abf + (size_t)(b * ITILES + it) * ADW;
  for (int kc = 0; kc < NKC; ++kc) {
    for (int idx = t; idx < 4096; idx += 256) {
      int cc = idx >> 6, ii = idx & 63;       // consecutive i -> coalesced global read
      int gi = it * 64 + ii;
      float v = 0.f;
      if (gi < LQ) v = x1[((size_t)b * CDIM + kc * 64 + cc) * LQ + gi] * rnq[ii];
      __hip_bfloat16 h = __float2bfloat16(v);
      tile[cc][ii] = *(unsigned short*)&h;
    }
    __syncthreads();
    for (int idx = t; idx < 2048; idx += 256) {
      int row = idx >> 5, kp = idx & 31;      // consecutive kp -> coalesced global write
      unsigned int lo = tile[kp * 2][row], hi = tile[kp * 2 + 1][row];
      blob[row * 320 + kc * 32 + kp] = lo | (hi << 16);
    }
    __syncthreads();
  }
}

// ---------------- prep: normalize x2 over C, emit MFMA-fragment-order B blob ----------------
// Bbf[n][mc] region (BMC bytes): granule g = (kc*2+ks)*16*64 + jf*64 + lane, lane = q*16+l15.
// Granule holds B[col = mc*256 + jf*16 + l15][k = kc*64 + ks*32 + q*8 .. +7] as 8 bf16.
__global__ __launch_bounds__(256) void prep_s(const float* __restrict__ x2,
                                              char* __restrict__ Bbf) {
  const int mc = blockIdx.x;   // 0..8
  const int n  = blockIdx.y;   // 0..31
  const int t  = threadIdx.x;
  __shared__ float rns[256];
  __shared__ unsigned short tile[64][266];   // [c][j], 266 stride -> conflict-lite column reads

  const int j = mc * 256 + t;
  float ss = 0.f;
  if (j < MS) {
    for (int c = 0; c < CDIM; ++c) {
      float v = x2[((size_t)n * CDIM + c) * MS + j];
      ss += v * v;
    }
  }
  rns[t] = (j < MS) ? rsqrtf(ss) : 0.f;
  __syncthreads();

  char* blob = Bbf + ((size_t)n * NJC + mc) * BMC;
  for (int kc = 0; kc < NKC; ++kc) {
    for (int idx = t; idx < 16384; idx += 256) {
      int cc = idx >> 8, jj = idx & 255;      // consecutive jj -> coalesced global read
      int gj = mc * 256 + jj;
      float v = 0.f;
      if (gj < MS) v = x2[((size_t)n * CDIM + kc * 64 + cc) * MS + gj] * rns[jj];
      __hip_bfloat16 h = __float2bfloat16(v);
      tile[cc][jj] = *(unsigned short*)&h;
    }
    __syncthreads();
    for (int g = t; g < 2048; g += 256) {     // consecutive g -> coalesced 16B global writes
      int ks = g >> 10, jf = (g >> 6) & 15, ln = g & 63;
      int qq = ln >> 4, cl = ln & 15;
      int col = jf * 16 + cl, k0 = ks * 32 + qq * 8;
      unsigned int u0 = (unsigned int)tile[k0 + 0][col] | ((unsigned int)tile[k0 + 1][col] << 16);
      unsigned int u1 = (unsigned int)tile[k0 + 2][col] | ((unsigned int)tile[k0 + 3][col] << 16);
      unsigned int u2 = (unsigned int)tile[k0 + 4][col] | ((unsigned int)tile[k0 + 5][col] << 16);
      unsigned int u3 = (unsigned int)tile[k0 + 6][col] | ((unsigned int)tile[k0 + 7][col] << 16);
      int4 w; w.x = u0; w.y = u1; w.z = u2; w.w = u3;
      *(int4*)(blob + (size_t)kc * 32768 + (size_t)g * 16) = w;
    }
    __syncthreads();
  }
}

// ---------------- main: A in LDS (XOR-swizzled, barrier-free K loop), B direct from global ----------------
// 1-D grid 14336. Decode for XCD L2 locality: xcd = bid&7 gets classes n = xcd*4 .. xcd*4+3.
__global__ __launch_bounds__(256, 2) void gemm_topk(const int4* __restrict__ Abf,
                                                    const char* __restrict__ Bbf,
                                                    float* __restrict__ out) {
  const int bid = blockIdx.x;
  const int xcd = bid & 7;
  const int s   = bid >> 3;              // 0..1791
  const int n   = xcd * 4 + s / 448;     // 4 classes per XCD
  const int bx  = s % 448;               // = b*7 + it
  const int b   = bx / 7;
  const int t    = threadIdx.x;
  const int lane = t & 63, wave = t >> 6;
  const int l15  = lane & 15, q = lane >> 4;

  __shared__ __align__(16) char smem[ABYTES];   // A tile; reused for merge

  // ---- stage A once, XOR-swizzled: granule (i,g) stored at i*80 + (g ^ (i&7)) ----
  {
    const int4* gA = Abf + (size_t)bx * 5120;
    int4* sA = (int4*)smem;
    #pragma unroll
    for (int rep = 0; rep < 20; ++rep) {
      int g0 = t + rep * 256;
      int i = g0 / 80;
      int g = g0 - i * 80;
      sA[i * 80 + (g ^ (i & 7))] = gA[g0];
    }
  }
  __syncthreads();

  float t3[16][3];
  #pragma unroll
  for (int r = 0; r < 16; ++r) { t3[r][0] = NEG_INF; t3[r][1] = NEG_INF; t3[r][2] = NEG_INF; }

  // A fragment addressing: byte = (r*16+l15)*1280 + kc*128 + oct*16, oct = (ks*4+q) ^ (l15&7)
  const int swz  = l15 & 7;
  const int oct0 = (q ^ swz) * 16;
  const int oct1 = ((4 + q) ^ swz) * 16;
  const char* Ab = smem + l15 * 1280;

  // B fragment base for this (n, wave, lane); blob walks contiguously in 32 KB k-chunks
  const char* BnB = Bbf + (size_t)n * BN + wave * 4096 + lane * 16;

  short8 bcur[2][4], bnxt[2][4];
  int off = 0;
  #pragma unroll
  for (int ks = 0; ks < 2; ++ks)
    #pragma unroll
    for (int c = 0; c < 4; ++c)
      bcur[ks][c] = *(const short8*)(BnB + ks * 16384 + c * 1024);

  for (int mc = 0; mc < NJC; ++mc) {
    f32x4 acc[4][4];
    #pragma unroll
    for (int r = 0; r < 4; ++r)
      #pragma unroll
      for (int c = 0; c < 4; ++c) acc[r][c] = (f32x4){0.f, 0.f, 0.f, 0.f};

    #pragma unroll 2
    for (int kc = 0; kc < NKC; ++kc) {
      int offn = off + 32768;
      if (offn == BN) offn = 0;              // wrap: harmless re-read of class start
      #pragma unroll
      for (int ks = 0; ks < 2; ++ks)
        #pragma unroll
        for (int c = 0; c < 4; ++c)
          bnxt[ks][c] = *(const short8*)(BnB + offn + ks * 16384 + c * 1024);

      #pragma unroll
      for (int ks = 0; ks < 2; ++ks) {
        const int oct = ks ? oct1 : oct0;
        short8 af[4];
        #pragma unroll
        for (int r = 0; r < 4; ++r)
          af[r] = *(const short8*)(Ab + r * 20480 + kc * 128 + oct);
        #pragma unroll
        for (int r = 0; r < 4; ++r)
          #pragma unroll
          for (int c = 0; c < 4; ++c)
            acc[r][c] = __builtin_amdgcn_mfma_f32_16x16x32_bf16(af[r], bcur[ks][c], acc[r][c], 0, 0, 0);
      }
      #pragma unroll
      for (int ks = 0; ks < 2; ++ks)
        #pragma unroll
        for (int c = 0; c < 4; ++c) bcur[ks][c] = bnxt[ks][c];
      off = offn;
    }

    // fold this 256-col chunk into running top-3
    #pragma unroll
    for (int c = 0; c < 4; ++c) {
      const int jg = mc * JCHUNK + wave * 64 + c * 16 + l15;
      const bool jv = jg < MS;
      #pragma unroll
      for (int r = 0; r < 4; ++r)
        #pragma unroll
        for (int reg = 0; reg < 4; ++reg) {
          float sv = jv ? acc[r][c][reg] : NEG_INF;
          ins3(sv, t3[r * 4 + reg][0], t3[r * 4 + reg][1], t3[r * 4 + reg][2]);
        }
    }
  }

  // ---- merge per-lane top-3 across the 64 lanes holding each row ----
  __syncthreads();                          // all waves done reading A; reuse smem
  float* mrg = (float*)smem;                // 64 rows * 64 slots * 3 = 49152 B
  float* aux = (float*)(smem + 49152);      // 64 rows * 4 segs * 3 = 3072 B
  #pragma unroll
  for (int r = 0; r < 4; ++r)
    #pragma unroll
    for (int reg = 0; reg < 4; ++reg) {
      int row = r * 16 + q * 4 + reg;       // C/D layout: row = quad*4 + reg
      int col = wave * 16 + l15;            // storage slot only
      float* p = &mrg[(row * 64 + col) * 3];
      p[0] = t3[r * 4 + reg][0]; p[1] = t3[r * 4 + reg][1]; p[2] = t3[r * 4 + reg][2];
    }
  __syncthreads();
  {
    int row = t >> 2, seg = t & 3;
    float a = NEG_INF, bb = NEG_INF, cc = NEG_INF;
    for (int c0 = seg * 16; c0 < seg * 16 + 16; ++c0) {
      const float* p = &mrg[(row * 64 + c0) * 3];
      ins3(p[0], a, bb, cc); ins3(p[1], a, bb, cc); ins3(p[2], a, bb, cc);
    }
    aux[(row * 4 + seg) * 3 + 0] = a;
    aux[(row * 4 + seg) * 3 + 1] = bb;
    aux[(row * 4 + seg) * 3 + 2] = cc;
  }
  __syncthreads();
  if (t < 64) {
    float a = NEG_INF, bb = NEG_INF, cc = NEG_INF;
    for (int v = 0; v < 12; ++v) ins3(aux[t * 12 + v], a, bb, cc);
    float sum = a + bb + cc;                // padded rows contribute exactly 0
    for (int offr = 32; offr > 0; offr >>= 1) sum += __shfl_down(sum, offr);
    if (t == 0) atomicAdd(&out[b * NCLS + n], sum);
  }
}

extern "C" void kernel_launch(void* const* d_in, const int* in_sizes, int n_in,
                              void* d_out, int out_size, void* d_ws, size_t ws_size,
                              hipStream_t stream) {
  const float* x1 = (const float*)d_in[0];   // [64, 640, 441] fp32
  const float* x2 = (const float*)d_in[1];   // [32, 640, 2205] fp32
  float* out = (float*)d_out;                // [64, 32] fp32

  // workspace: Abf 36,700,160 B | Bbf 94,371,840 B  (total ~131 MB)
  unsigned short* Abf = (unsigned short*)d_ws;
  char* Bbf = (char*)d_ws + (size_t)BQ * ITILES * ABYTES;

  hipMemsetAsync(d_out, 0, BQ * NCLS * sizeof(float), stream);
  prep_q<<<dim3(ITILES, BQ), 256, 0, stream>>>(x1, Abf);
  prep_s<<<dim3(NJC, NCLS), 256, 0, stream>>>(x2, Bbf);
  gemm_topk<<<BQ * ITILES * NCLS, 256, 0, stream>>>((const int4*)Abf, Bbf, out);
}